// Round 1
// baseline (860.803 us; speedup 1.0000x reference)
//
#include <hip/hip_runtime.h>

// Liquid Neural Network scan, fp32, fused single kernel.
// One wave (64 lanes) per batch row b; lane j owns hidden unit j.
// x-row loads are wave-uniform -> scalar loads; h broadcast via LDS.

constexpr int T_STEPS = 512;
constexpr int IN_DIM  = 32;
constexpr int HID     = 64;

__global__ __launch_bounds__(64, 2)
void lnn_scan_kernel(const float* __restrict__ x,      // [B, T, 32]
                     const float* __restrict__ W_in,   // [32, 64]
                     const float* __restrict__ b_in,   // [64]
                     const float* __restrict__ W_rec,  // [64, 64]
                     const float* __restrict__ b_rec,  // [64]
                     const float* __restrict__ tau,    // [64]
                     const float* __restrict__ W_fc,   // [64, 1]
                     const float* __restrict__ b_fc,   // [1]
                     float* __restrict__ out)          // [B]
{
    const int j = threadIdx.x;   // hidden unit
    const int b = blockIdx.x;    // batch row (wave-uniform)

    __shared__ float hbuf[2][HID];

    // Per-lane weight columns (coalesced across lanes, cached after first blocks).
    float win[IN_DIM];
#pragma unroll
    for (int i = 0; i < IN_DIM; ++i) win[i] = W_in[i * HID + j];

    float wrec[HID];
#pragma unroll
    for (int k = 0; k < HID; ++k) wrec[k] = W_rec[k * HID + j];

    const float bias    = b_in[j] + b_rec[j];
    const float inv_tau = 1.0f / tau[j];   // once, full-precision div

    const float* __restrict__ xrow = x + (size_t)b * T_STEPS * IN_DIM;

    float h = 0.0f;

    // Prefetch row 0 (uniform address -> s_load into SGPRs).
    float xc[IN_DIM];
#pragma unroll
    for (int i = 0; i < IN_DIM; ++i) xc[i] = xrow[i];

    for (int t = 0; t < T_STEPS; ++t) {
        // Issue next-row loads early; clamp on last iteration (stays in-bounds).
        const int tn = (t + 1 < T_STEPS) ? (t + 1) : t;
        const float* __restrict__ xn = xrow + (size_t)tn * IN_DIM;
        float xnext[IN_DIM];
#pragma unroll
        for (int i = 0; i < IN_DIM; ++i) xnext[i] = xn[i];

        // Broadcast h across the wave through LDS (double-buffered).
        hbuf[t & 1][j] = h;
        __syncthreads();

        // z = b_in[j] + b_rec[j] + x_t . W_in[:,j]
        float z = bias;
#pragma unroll
        for (int i = 0; i < IN_DIM; ++i) z = fmaf(xc[i], win[i], z);

        // z += h . W_rec[:,j]  (uniform-address float4 LDS reads = broadcast)
        const float4* hb = (const float4*)hbuf[t & 1];
#pragma unroll
        for (int q = 0; q < HID / 4; ++q) {
            const float4 hv = hb[q];
            z = fmaf(hv.x, wrec[4 * q + 0], z);
            z = fmaf(hv.y, wrec[4 * q + 1], z);
            z = fmaf(hv.z, wrec[4 * q + 2], z);
            z = fmaf(hv.w, wrec[4 * q + 3], z);
        }

        // tanh(z) = 1 - 2/(exp(2z)+1); saturates correctly at +/-inf.
        const float e  = __expf(2.0f * z);
        const float th = 1.0f - 2.0f * __builtin_amdgcn_rcpf(e + 1.0f);

        // h += (tanh - h) / tau
        h = fmaf(th - h, inv_tau, h);

        // rotate prefetch buffer
#pragma unroll
        for (int i = 0; i < IN_DIM; ++i) xc[i] = xnext[i];
    }

    // out[b] = h . W_fc + b_fc  (wave-wide reduction)
    float v = h * W_fc[j];
#pragma unroll
    for (int off = 32; off > 0; off >>= 1)
        v += __shfl_down(v, off);
    if (j == 0) out[b] = v + b_fc[0];
}

extern "C" void kernel_launch(void* const* d_in, const int* in_sizes, int n_in,
                              void* d_out, int out_size, void* d_ws, size_t ws_size,
                              hipStream_t stream) {
    const float* x     = (const float*)d_in[0];
    const float* W_in  = (const float*)d_in[1];
    const float* b_in  = (const float*)d_in[2];
    const float* W_rec = (const float*)d_in[3];
    const float* b_rec = (const float*)d_in[4];
    const float* tau   = (const float*)d_in[5];
    const float* W_fc  = (const float*)d_in[6];
    const float* b_fc  = (const float*)d_in[7];
    float* out = (float*)d_out;

    const int B = out_size;  // 4096
    lnn_scan_kernel<<<B, HID, 0, stream>>>(x, W_in, b_in, W_rec, b_rec, tau,
                                           W_fc, b_fc, out);
}